// Round 9
// baseline (2675.653 us; speedup 1.0000x reference)
//
#include <hip/hip_runtime.h>
#include <math.h>

#define NBLK 256
#define NTHR 512
#define Bsz  32
#define Hsz  512
#define Vsz  32000
#define BH   (Bsz*Hsz)
#define LDP  516         // fp32 row stride for fallback (512 + 4 pad)
#define LDPB 520         // bf16 row stride (1040B: 16B-aligned, 2-way-free banks)
#define CBLK 250         // blocks doing logits (128 rows each)
#define EPS  0.0045f     // bf16 dot-product error coefficient (provable bound w/ margin)

// ---- ws layout (bytes) ----
#define WS_HBUF   0            // 2*BH floats = 131072
#define WS_PACKED 131072       // 32 x 128B (ull key64 per b)
#define WS_PLB    135168       // 32 x 128B (u32 lb-key per b, barrier-free monotone share)
#define WS_BAR    139264       // 17 x 128B tree barrier
#define WS_WPACK  143360       // 250*8*16*1024 = 32768000 (bf16 B-frags)
#define WS_WNORM  32911360     // 32000 floats (EPS * ||w_n||2)
#define WS_CBAR   33039360     // 32 x 128B monotone cluster counters
#define WS_NEEDED 33043456

// Seed for packed[b]: high word 0 (any real key32(lg)>=1 wins atomicMax),
// low word ~1u so an untouched slot decodes to tok=1 (valid), never -1.
#define PACKED_SEED 0x00000000FFFFFFFEull

typedef short short8 __attribute__((ext_vector_type(8)));
typedef float f32x4  __attribute__((ext_vector_type(4)));

struct Args {
  const float* h0_init;
  const float* emb;
  const float* Wih0; const float* Whh0; const float* bih0; const float* bhh0;
  const float* Wih1; const float* Whh1; const float* bih1; const float* bhh1;
  const float* Wout; const float* bout;
  const int*   maxn;
  float* out;
  float* hbuf;                 // [2*BH] h0,h1 (single-buffered)
  unsigned long long* packed;  // final fp32-key argmax per b (128B stride)
  unsigned* plb;               // per-b max lower-bound key (monotone, barrier-free)
  unsigned* bar;
  unsigned* cbar;              // 32 monotone cluster counters (128B stride)
  const unsigned* wpack;       // bf16 B-fragment packed Wout
  const float* wnormE;         // EPS * ||bf16(w_n)||_2
};

// ---- bf16 helpers (consistent RNE everywhere) ----
__device__ __forceinline__ unsigned short bf16_rne(float f){
  unsigned u = __float_as_uint(f);
  unsigned r = u + 0x7FFFu + ((u >> 16) & 1u);
  return (unsigned short)(r >> 16);
}
__device__ __forceinline__ float bf16v(float f){   // value after bf16 RNE rounding
  unsigned u = ((unsigned)bf16_rne(f)) << 16;
  return __uint_as_float(u);
}
__device__ __forceinline__ unsigned short bf16_ru(float f){  // round toward +inf
  unsigned u = __float_as_uint(f);
  unsigned t = u >> 16;
  if (!(u & 0x80000000u)) { if (u & 0xFFFFu) t++; }  // positive: bump; negative: trunc
  return (unsigned short)t;
}
__device__ __forceinline__ unsigned key32(float f){  // monotone float->uint
  unsigned u = __float_as_uint(f);
  return (u & 0x80000000u) ? ~u : (u | 0x80000000u);
}

// ---- coherent (L3-point) accessors ----
__device__ __forceinline__ unsigned long long cload8(const void* p){
  return __hip_atomic_load((const unsigned long long*)p,
                           __ATOMIC_RELAXED, __HIP_MEMORY_SCOPE_AGENT);
}
__device__ __forceinline__ unsigned cload4u(const unsigned* p){
  return __hip_atomic_load(p, __ATOMIC_RELAXED, __HIP_MEMORY_SCOPE_AGENT);
}
__device__ __forceinline__ void cstore4(float* p, float v){
  __hip_atomic_store(p, v, __ATOMIC_RELAXED, __HIP_MEMORY_SCOPE_AGENT);
}
__device__ __forceinline__ void cstore4u(unsigned* p, unsigned v){
  __hip_atomic_store(p, v, __ATOMIC_RELAXED, __HIP_MEMORY_SCOPE_AGENT);
}
__device__ __forceinline__ void cstore8(void* p, unsigned long long v){
  __hip_atomic_store((unsigned long long*)p, v,
                     __ATOMIC_RELAXED, __HIP_MEMORY_SCOPE_AGENT);
}

// non-temporal 16B load (one-time wpack hoist; avoid L2 pollution)
__device__ __forceinline__ short8 ntload8(const void* p){
  return __builtin_nontemporal_load((const short8*)p);
}

// ---- 2-level tree barrier (relaxed, contention-sharded), 256 blocks ----
__device__ __forceinline__ void gridbar(unsigned* bar, int bid){
  __syncthreads();
  if (threadIdx.x == 0){
    asm volatile("s_waitcnt vmcnt(0)" ::: "memory");
    const int g = bid & 7;
    unsigned* gcnt = bar + g*32;
    unsigned* root = bar + 8*32;
    unsigned* gen  = bar + (9+g)*32;
    unsigned mygen = __hip_atomic_load(gen, __ATOMIC_RELAXED, __HIP_MEMORY_SCOPE_AGENT);
    unsigned go = __hip_atomic_fetch_add(gcnt, 1u, __ATOMIC_RELAXED, __HIP_MEMORY_SCOPE_AGENT);
    if (go == 31u){
      unsigned ro = __hip_atomic_fetch_add(root, 1u, __ATOMIC_RELAXED, __HIP_MEMORY_SCOPE_AGENT);
      if (ro == 7u){
        #pragma unroll
        for (int i = 0; i < 8; ++i)
          __hip_atomic_store(bar + i*32, 0u, __ATOMIC_RELAXED, __HIP_MEMORY_SCOPE_AGENT);
        __hip_atomic_store(root, 0u, __ATOMIC_RELAXED, __HIP_MEMORY_SCOPE_AGENT);
        asm volatile("s_waitcnt vmcnt(0)" ::: "memory");
        #pragma unroll
        for (int i = 0; i < 8; ++i)
          __hip_atomic_fetch_add(bar + (9+i)*32, 1u, __ATOMIC_RELAXED, __HIP_MEMORY_SCOPE_AGENT);
      }
    }
    while (__hip_atomic_load(gen, __ATOMIC_RELAXED, __HIP_MEMORY_SCOPE_AGENT) == mygen){
      __builtin_amdgcn_s_sleep(1);
    }
  }
  __syncthreads();
}

// ---- monotone 8-block cluster barrier (no reset -> no reset/release race) ----
__device__ __forceinline__ void cluster_sync(unsigned* cnt, unsigned target){
  __syncthreads();
  if (threadIdx.x == 0){
    asm volatile("s_waitcnt vmcnt(0)" ::: "memory");
    __hip_atomic_fetch_add(cnt, 1u, __ATOMIC_RELAXED, __HIP_MEMORY_SCOPE_AGENT);
    while (__hip_atomic_load(cnt, __ATOMIC_RELAXED, __HIP_MEMORY_SCOPE_AGENT) < target){
      __builtin_amdgcn_s_sleep(1);
    }
  }
  __syncthreads();
}

// stage 32x512 floats global -> LDS as bf16 (row stride LDPB shorts).
// bf16_rne applied during staging: consumers see exactly the values the
// old fp32-stage + per-fragment-convert pipeline produced.
__device__ __forceinline__ void stage_h16(const float* g, unsigned short* s16, int tid){
  const unsigned long long* gd = (const unsigned long long*)g;
  #pragma unroll
  for (int n = 0; n < 16; ++n){
    int idx = n*512 + tid;          // float-pair index over 32*256
    int row = idx >> 8;
    int col2 = idx & 255;
    unsigned long long v = __hip_atomic_load(gd + idx, __ATOMIC_RELAXED,
                                             __HIP_MEMORY_SCOPE_AGENT);
    unsigned short b0 = bf16_rne(__uint_as_float((unsigned)v));
    unsigned short b1 = bf16_rne(__uint_as_float((unsigned)(v >> 32)));
    *(unsigned*)&s16[row*LDPB + col2*2] = (unsigned)b0 | ((unsigned)b1 << 16);
  }
}

// stage 32x512 floats global -> LDS fp32 (row stride LDP) — fallback kernel
__device__ __forceinline__ void stage_h(const float* g, float* s, int tid){
  const unsigned long long* gd = (const unsigned long long*)g;
  #pragma unroll
  for (int n = 0; n < 16; ++n){
    int idx = n*512 + tid;
    int row = idx >> 8;
    int col = idx & 255;
    unsigned long long v = __hip_atomic_load(gd + idx, __ATOMIC_RELAXED,
                                             __HIP_MEMORY_SCOPE_AGENT);
    *(unsigned long long*)(s + row*LDP + col*2) = v;
  }
}

// stage one 512-float row global -> LDS, coherent 8B loads
__device__ __forceinline__ void stage_row(const float* g, float* s, int tid){
  if (tid < 256){
    unsigned long long v = __hip_atomic_load((const unsigned long long*)g + tid,
                                             __ATOMIC_RELAXED, __HIP_MEMORY_SCOPE_AGENT);
    *(unsigned long long*)(s + tid*2) = v;
  }
}

__device__ __forceinline__ float red8(float v){
  v += __shfl_xor(v, 1); v += __shfl_xor(v, 2); v += __shfl_xor(v, 4);
  return v;
}
__device__ __forceinline__ float dot4acc(float4 w, float4 x, float acc){
  return fmaf(w.x,x.x, fmaf(w.y,x.y, fmaf(w.z,x.z, fmaf(w.w,x.w, acc))));
}

// 3-gate dot-512 over one row (8 lanes per oct). Same summation order
// everywhere -> h trajectories bitwise identical across restructurings.
__device__ __forceinline__ void dot3(const float* row, const float* W, int j,
                                     int lane8, float& g0, float& g1, float& g2){
  const float* w = W + (size_t)j * Hsz;
  float a0 = 0.f, a1 = 0.f, a2 = 0.f;
  #pragma unroll 4
  for (int i = 0; i < 16; ++i){
    int k = i*32 + lane8*4;
    float4 v = *(const float4*)(row + k);
    a0 = dot4acc(*(const float4*)(w + k),            v, a0);
    a1 = dot4acc(*(const float4*)(w + 512*512 + k),  v, a1);
    a2 = dot4acc(*(const float4*)(w + 2*512*512 + k),v, a2);
  }
  g0 = red8(a0); g1 = red8(a1); g2 = red8(a2);
}

__device__ __forceinline__ void gru_oct(
    const float* xrow, const float* hrow,
    const float* Wih, const float* Whh,
    const float* bih, const float* bhh,
    int j, int lane8, float* hout_g)
{
  const float* wir = Wih + (size_t)j * Hsz;
  const float* whr = Whh + (size_t)j * Hsz;
  float ar=0.f, az=0.f, an=0.f, hr=0.f, hz=0.f, hn=0.f;
  #pragma unroll 4
  for (int i = 0; i < 16; ++i){
    int k = i*32 + lane8*4;
    float4 xv = *(const float4*)(xrow + k);
    float4 hv = *(const float4*)(hrow + k);
    ar = dot4acc(*(const float4*)(wir + k),            xv, ar);
    az = dot4acc(*(const float4*)(wir + 512*512 + k),  xv, az);
    an = dot4acc(*(const float4*)(wir + 2*512*512 + k),xv, an);
    hr = dot4acc(*(const float4*)(whr + k),            hv, hr);
    hz = dot4acc(*(const float4*)(whr + 512*512 + k),  hv, hz);
    hn = dot4acc(*(const float4*)(whr + 2*512*512 + k),hv, hn);
  }
  ar = red8(ar); az = red8(az); an = red8(an);
  hr = red8(hr); hz = red8(hz); hn = red8(hn);
  if (lane8 == 0){
    float r = 1.f/(1.f + expf(-(ar + bih[j]       + hr + bhh[j])));
    float z = 1.f/(1.f + expf(-(az + bih[Hsz+j]   + hz + bhh[Hsz+j])));
    float n = tanhf(an + bih[2*Hsz+j] + r*(hn + bhh[2*Hsz+j]));
    cstore4(hout_g, (1.f - z)*n + z*hrow[j]);
  }
}

// ================= repack: Wout fp32 -> bf16 B-fragments + row norms =================
__global__ __launch_bounds__(512) void repack_kernel(const float* __restrict__ Wout,
                                                     unsigned* __restrict__ wpack,
                                                     float* __restrict__ wnormE){
  const int rb = blockIdx.x;            // 0..249
  const int g = threadIdx.x >> 6;       // wave
  const int lane = threadIdx.x & 63;
  const int n = rb*128 + g*16 + (lane & 15);
  const int kq = (lane >> 4) * 8;
  float sumsq = 0.f;
  for (int c = 0; c < 16; ++c){
    const float* p = Wout + (size_t)n*512 + c*32 + kq;
    float4 f0 = *(const float4*)p;
    float4 f1 = *(const float4*)(p + 4);
    unsigned short s0 = bf16_rne(f0.x), s1 = bf16_rne(f0.y),
                   s2 = bf16_rne(f0.z), s3 = bf16_rne(f0.w),
                   s4 = bf16_rne(f1.x), s5 = bf16_rne(f1.y),
                   s6 = bf16_rne(f1.z), s7 = bf16_rne(f1.w);
    float v;
    v = __uint_as_float(((unsigned)s0)<<16); sumsq += v*v;
    v = __uint_as_float(((unsigned)s1)<<16); sumsq += v*v;
    v = __uint_as_float(((unsigned)s2)<<16); sumsq += v*v;
    v = __uint_as_float(((unsigned)s3)<<16); sumsq += v*v;
    v = __uint_as_float(((unsigned)s4)<<16); sumsq += v*v;
    v = __uint_as_float(((unsigned)s5)<<16); sumsq += v*v;
    v = __uint_as_float(((unsigned)s6)<<16); sumsq += v*v;
    v = __uint_as_float(((unsigned)s7)<<16); sumsq += v*v;
    uint4 u;
    u.x = (unsigned)s0 | ((unsigned)s1<<16);
    u.y = (unsigned)s2 | ((unsigned)s3<<16);
    u.z = (unsigned)s4 | ((unsigned)s5<<16);
    u.w = (unsigned)s6 | ((unsigned)s7<<16);
    *(uint4*)(wpack + (size_t)(((rb*8+g)*16 + c))*256 + lane*4) = u;
  }
  sumsq += __shfl_xor(sumsq, 16);
  sumsq += __shfl_xor(sumsq, 32);
  if (lane < 16) wnormE[n] = EPS * sqrtf(sumsq);
}

// ================= main cooperative kernel (MFMA path) =================
// Batch-cluster decomposition (R8): block bid owns batch b = bid>>3, j-range
// [s*64,+64), s = bid&7. Barriers/step: 1 cluster sync + 2 global bars.
// R9: shB is staged as BF16 (rows LDPB=520, 16B-aligned). A-fragments are
// direct ds_read_b128 from shB16 — the 16KB af buffer, its 2-pass build, and
// 2 syncthreads/step are deleted. hnorm reads shB16 (values are bf16v(h1) —
// identical); gh1 uses a 2KB fp32 h1row stage; rescore reads its few h-rows
// from global h1g via agent-scope loads (L1-stale-safe). All consumed values
// bitwise identical to R8. AGPR-pinned wpack fragments (R6). PACKED_SEED.
__global__ __launch_bounds__(NTHR, 1) void decoder_kernel(Args a){
  const int tid = threadIdx.x;
  const int bid = blockIdx.x;
  const int wave = tid >> 6;
  const int lane = tid & 63;
  const int b  = bid >> 3;          // owned batch
  const int s  = bid & 7;           // cluster sub-index
  const int j0 = s * 64;            // owned j-range start
  const int T = a.maxn[0];
  float* h0g = a.hbuf;
  float* h1g = a.hbuf + BH;

  __shared__ __align__(16) unsigned short shB16[Bsz*LDPB];  // h1 bf16 mirror (33 KB)
  __shared__ float h0row[LDP];                   // h0_t[b] fp32 (cluster-staged)
  __shared__ float h1row[LDP];                   // h1_t[b] fp32 (for gh1 dot)
  __shared__ unsigned long long ubq8[128*8];     // packed bf16 upper bounds (8 KB)
  __shared__ float ghA[3][64];                   // gh0 gates for owned j's
  __shared__ float ghB[3][64];                   // gh1 gates for owned j's
  __shared__ float h0own[64];                    // h0_{t}[b][owned j]
  __shared__ float h1own[64];                    // h1_{t}[b][owned j]
  __shared__ unsigned lbmaxL[32];
  __shared__ unsigned maxlbL[32];
  __shared__ float hnormL[32];
  __shared__ int sh_tok0;
  __shared__ int candCnt;
  __shared__ int candList[512];
  unsigned short* ubq16 = (unsigned short*)ubq8;

  // ---- hoisted step-invariant state: wave's 16 B-fragments -> AGPRs ----
  short8 bw[16];
  float bias = 0.f, wn = 0.f;
  if (bid < CBLK){
    const unsigned* wbase = a.wpack + (size_t)((bid*8 + wave)*16)*256 + lane*4;
    #pragma unroll
    for (int c = 0; c < 16; ++c){
      bw[c] = ntload8(wbase + c*256);
      asm volatile("" : "+a"(bw[c]));            // pin to AGPR class
    }
    int n = bid*128 + wave*16 + (lane & 15);
    bias = a.bout[n];
    wn = a.wnormE[n];
  }

  // ---- prologue: own-h init, h0row/h1row stage, gh for step 0 ----
  if (tid < 64){
    h0own[tid] = a.h0_init[(size_t)b*Hsz + j0 + tid];
    h1own[tid] = a.h0_init[BH + (size_t)b*Hsz + j0 + tid];
  }
  stage_row(a.h0_init + (size_t)b*Hsz, h0row, tid);
  stage_row(a.h0_init + BH + (size_t)b*Hsz, h1row, tid);
  __syncthreads();
  {
    int oct = tid >> 3, lane8 = tid & 7;
    int j = j0 + oct;
    float hr, hz, hn;  dot3(h0row, a.Whh0, j, lane8, hr, hz, hn);
    float kr, kz, kn;  dot3(h1row, a.Whh1, j, lane8, kr, kz, kn);
    if (lane8 == 0){
      ghA[0][oct] = hr; ghA[1][oct] = hz; ghA[2][oct] = hn;
      ghB[0][oct] = kr; ghB[1][oct] = kz; ghB[2][oct] = kn;
    }
  }
  __syncthreads();

  unsigned ctarget = 0;
  for (int t = 0; t < T; ++t){
    // ---- Phase A: GRU0 input-side for owned batch (no stage) ----
    if (tid == 0){
      int tok = 1;
      if (t > 0){
        tok = (int)(~(unsigned)(cload8(&a.packed[b*16]) & 0xffffffffULL));
        if ((unsigned)tok >= (unsigned)Vsz) tok = 1;  // safety clamp
      }
      sh_tok0 = tok;
    }
    __syncthreads();
    {
      int oct = tid >> 3, lane8 = tid & 7;
      int j = j0 + oct;
      const float* xrow = a.emb + (size_t)sh_tok0 * Hsz;
      float ar, az, an;  dot3(xrow, a.Wih0, j, lane8, ar, az, an);
      if (lane8 == 0){
        float hr = ghA[0][oct], hz = ghA[1][oct], hn = ghA[2][oct];
        float r = 1.f/(1.f + expf(-(ar + a.bih0[j]       + hr + a.bhh0[j])));
        float z = 1.f/(1.f + expf(-(az + a.bih0[Hsz+j]   + hz + a.bhh0[Hsz+j])));
        float n = tanhf(an + a.bih0[2*Hsz+j] + r*(hn + a.bhh0[2*Hsz+j]));
        float hnew = (1.f - z)*n + z*h0own[oct];
        cstore4(h0g + (size_t)b*Hsz + j, hnew);
        h0own[oct] = hnew;
      }
    }
    ctarget += 8;
    cluster_sync(a.cbar + b*32, ctarget);      // 8-block h0 exchange

    // ---- Phase B: harvest token t-1 (cluster leader), seed packed/plb;
    //      2KB cluster stage of h0_t[b]; GRU1 input-side + combine ----
    if (s == 0 && tid == 0){
      if (t > 0){
        unsigned long long p = cload8(&a.packed[b*16]);
        int tok = (int)(~(unsigned)(p & 0xffffffffULL));
        a.out[(size_t)b*T + (t-1)] = (float)tok;
      }
      cstore8(&a.packed[b*16], PACKED_SEED);
      cstore4u(&a.plb[b*32], 0u);
    }
    stage_row(h0g + (size_t)b*Hsz, h0row, tid);  // h0_t[b]
    __syncthreads();
    {
      int oct = tid >> 3, lane8 = tid & 7;
      int j = j0 + oct;
      float ar, az, an;  dot3(h0row, a.Wih1, j, lane8, ar, az, an);
      if (lane8 == 0){
        float hr = ghB[0][oct], hz = ghB[1][oct], hn = ghB[2][oct];
        float r = 1.f/(1.f + expf(-(ar + a.bih1[j]       + hr + a.bhh1[j])));
        float z = 1.f/(1.f + expf(-(az + a.bih1[Hsz+j]   + hz + a.bhh1[Hsz+j])));
        float n = tanhf(an + a.bih1[2*Hsz+j] + r*(hn + a.bhh1[2*Hsz+j]));
        float hnew = (1.f - z)*n + z*h1own[oct];
        cstore4(h1g + (size_t)b*Hsz + j, hnew);
        h1own[oct] = hnew;
      }
    }
    gridbar(a.bar, bid);

    // ---- Phase C: stage h1->shB16 (bf16, CBLK only) + h1row (all);
    //      gh precompute for t+1; MFMA logits + bounds + prune + rescore ----
    if (bid < CBLK) stage_h16(h1g, shB16, tid);
    stage_row(h1g + (size_t)b*Hsz, h1row, tid);  // h1_t[b] fp32
    if (tid < 32) lbmaxL[tid] = 0u;
    if (tid == 0) candCnt = 0;
    __syncthreads();
    // gh precompute (all blocks): h0row = h0_t[b] (staged in B, untouched),
    // h1row = h1_t[b]. Same dot3 order as R8 -> bitwise identical.
    {
      int oct = tid >> 3, lane8 = tid & 7;
      int j = j0 + oct;
      float hr, hz, hn;  dot3(h0row, a.Whh0, j, lane8, hr, hz, hn);
      float kr, kz, kn;  dot3(h1row, a.Whh1, j, lane8, kr, kz, kn);
      if (lane8 == 0){
        ghA[0][oct] = hr; ghA[1][oct] = hz; ghA[2][oct] = hn;
        ghB[0][oct] = kr; ghB[1][oct] = kz; ghB[2][oct] = kn;
      }
    }
    if (bid < CBLK){
      // re-assert AGPR residency for the loop-carried fragment values
      #pragma unroll
      for (int c = 0; c < 16; ++c) asm volatile("" : "+a"(bw[c]));

      // h-norms from bf16-resident shB16 (values ARE bf16v(h1))
      if (tid < 256){
        int hb = tid >> 3, lane8 = tid & 7;
        float sq = 0.f;
        #pragma unroll
        for (int i = 0; i < 8; ++i){
          short8 sv = *(const short8*)&shB16[hb*LDPB + i*64 + lane8*8];
          #pragma unroll
          for (int q = 0; q < 8; ++q){
            float v = __uint_as_float(((unsigned)(unsigned short)sv[q]) << 16);
            sq = fmaf(v, v, sq);
          }
        }
        sq = red8(sq);
        if (lane8 == 0) hnormL[hb] = sqrtf(sq);
      }

      // MFMA: A-operand via direct ds_read_b128 of shB16 (no af staging)
      f32x4 accs[2];
      #pragma unroll
      for (int mt = 0; mt < 2; ++mt){
        f32x4 acc = {0.f, 0.f, 0.f, 0.f};
        const unsigned short* arow = shB16 + (mt*16 + (lane & 15))*LDPB + (lane >> 4)*8;
        #pragma unroll
        for (int c = 0; c < 16; ++c){
          short8 av = *(const short8*)(arow + c*32);
          acc = __builtin_amdgcn_mfma_f32_16x16x32_bf16(av, bw[c], acc, 0, 0, 0);
        }
        accs[mt] = acc;
      }
      __syncthreads();   // hnormL ready for epilogue
      // epilogue: D[m][n], m = mt*16 + (lane>>4)*4 + r, n = bid*128 + wave*16 + (lane&15)
      {
        int n_loc = wave*16 + (lane & 15);
        int quad = lane >> 4;
        #pragma unroll
        for (int mt = 0; mt < 2; ++mt){
          unsigned long long pk = 0ULL;
          #pragma unroll
          for (int r = 0; r < 4; ++r){
            int m = mt*16 + quad*4 + r;
            float lg = accs[mt][r] + bias;
            float mg = wn * hnormL[m];
            float lb = lg - mg;
            float ub = lg + mg;
            pk |= ((unsigned long long)bf16_ru(ub)) << (16*r);
            unsigned lk = key32(lb), o;
            o = __shfl_xor(lk, 1); lk = lk > o ? lk : o;
            o = __shfl_xor(lk, 2); lk = lk > o ? lk : o;
            o = __shfl_xor(lk, 4); lk = lk > o ? lk : o;
            o = __shfl_xor(lk, 8); lk = lk > o ? lk : o;
            if ((lane & 15) == 0) atomicMax(&lbmaxL[m], lk);
          }
          ubq8[n_loc*8 + mt*4 + quad] = pk;   // ushort idx n_loc*32 + m
        }
      }
      __syncthreads();
      // publish local max-lb to global plb (fire-and-forget; monotone tighten)
      if (tid < 32) atomicMax(&a.plb[tid*32], lbmaxL[tid]);
      // scan all 4096 (n_loc, b) ub entries vs LOCAL lbmax
      for (int u = 0; u < 8; ++u){
        int idx = u*512 + tid;                // n_loc = idx>>5, b = idx&31
        unsigned short q = ubq16[idx];
        float uf = __uint_as_float(((unsigned)q) << 16);
        if (key32(uf) >= lbmaxL[idx & 31]){
          int pos = atomicAdd(&candCnt, 1);
          if (pos < 512) candList[pos] = idx;
        }
      }
      __syncthreads();
      // re-read plb (other blocks' publishes have been landing meanwhile)
      if (tid < 32){
        unsigned g = cload4u(&a.plb[tid*32]);
        unsigned l = lbmaxL[tid];
        maxlbL[tid] = g > l ? g : l;
      }
      __syncthreads();
      // exact fp32 rescore of surviving candidates (wave-per-candidate).
      // h-row read from global h1g via agent-scope loads (L2-resident, few).
      auto rescore = [&](int cidx){
        int n_loc = cidx >> 5, rb = cidx & 31;
        unsigned short q = ubq16[cidx];
        float uf = __uint_as_float(((unsigned)q) << 16);
        if (key32(uf) < maxlbL[rb]) return;      // tightened skip
        int n = bid*128 + n_loc;
        const float* wrow = a.Wout + (size_t)n*512 + lane*8;
        const unsigned long long* hq =
            (const unsigned long long*)(h1g + (size_t)rb*Hsz) + lane*4;
        unsigned long long q0 = cload8(hq),     q1 = cload8(hq + 1);
        unsigned long long q2 = cload8(hq + 2), q3 = cload8(hq + 3);
        float4 x0 = make_float4(__uint_as_float((unsigned)q0),
                                __uint_as_float((unsigned)(q0 >> 32)),
                                __uint_as_float((unsigned)q1),
                                __uint_as_float((unsigned)(q1 >> 32)));
        float4 x1 = make_float4(__uint_as_float((unsigned)q2),
                                __uint_as_float((unsigned)(q2 >> 32)),
                                __uint_as_float((unsigned)q3),
                                __uint_as_float((unsigned)(q3 >> 32)));
        float4 w0 = *(const float4*)wrow,      w1 = *(const float4*)(wrow + 4);
        float d = dot4acc(w0, x0, 0.f);
        d = dot4acc(w1, x1, d);
        d += __shfl_xor(d, 1);  d += __shfl_xor(d, 2);  d += __shfl_xor(d, 4);
        d += __shfl_xor(d, 8);  d += __shfl_xor(d, 16); d += __shfl_xor(d, 32);
        if (lane == 0){
          float lg = d + a.bout[n];
          unsigned long long key =
              (((unsigned long long)key32(lg)) << 32) | (unsigned)(~(unsigned)n);
          atomicMax(&a.packed[rb*16], key);
        }
      };
      int nc = candCnt;
      if (nc <= 512){
        for (int ci = wave; ci < nc; ci += 8) rescore(candList[ci]);
      } else {
        // overflow safety net (cannot trigger with these margins): exact-check all
        for (int ci = wave; ci < 4096; ci += 8) rescore(ci);
      }
    }
    gridbar(a.bar, bid);
  }

  // ---- final harvest + final hidden states ----
  if (bid == 0 && tid < Bsz){
    unsigned long long p = cload8(&a.packed[tid*16]);
    int tok = (int)(~(unsigned)(p & 0xffffffffULL));
    a.out[tid*T + (T-1)] = (float)tok;
  }
  int e = bid*NTHR + tid;
  if (e < BH/2){
    unsigned long long v0 = cload8((const unsigned long long*)h0g + e);
    unsigned long long v1 = cload8((const unsigned long long*)h1g + e);
    *((unsigned long long*)(a.out + Bsz*T) + e)      = v0;
    *((unsigned long long*)(a.out + Bsz*T + BH) + e) = v1;
  }
}

// ================= fallback (round-4 fp32 path) if ws too small =================
__global__ __launch_bounds__(NTHR, 1) void decoder_kernel_fb(Args a){
  const int tid = threadIdx.x;
  const int bid = blockIdx.x;
  const int T = a.maxn[0];
  float* h0g = a.hbuf;
  float* h1g = a.hbuf + BH;
  __shared__ float shA[Bsz*LDP];
  __shared__ float shB[Bsz*LDP];
  __shared__ unsigned long long lbest[32*32];
  __shared__ int sh_tok[Bsz];

  for (int t = 0; t < T; ++t){
    if (t == 0) stage_h(a.h0_init, shA, tid);
    if (tid < Bsz){
      int tok;
      if (t == 0) tok = 1;
      else {
        tok = (int)(~(unsigned)(cload8(&a.packed[tid*16]) & 0xffffffffULL));
        if ((unsigned)tok >= (unsigned)Vsz) tok = 1;
      }
      sh_tok[tid] = tok;
    }
    __syncthreads();
    {
      int oct = tid >> 3, lane8 = tid & 7;
      int b = oct & 31, jj = oct >> 5;
      int j = bid*2 + jj;
      const float* xrow = a.emb + (size_t)sh_tok[b] * Hsz;
      gru_oct(xrow, shA + b*LDP, a.Wih0, a.Whh0, a.bih0, a.bhh0,
              j, lane8, h0g + b*Hsz + j);
    }
    gridbar(a.bar, bid);
    if (bid == 0 && tid < Bsz){
      if (t > 0){
        unsigned long long p = cload8(&a.packed[tid*16]);
        a.out[tid*T + (t-1)] = (float)((int)(~(unsigned)(p & 0xffffffffULL)));
      }
      cstore8(&a.packed[tid*16], PACKED_SEED);
    }
    stage_h(h0g, shA, tid);
    if (t == 0) stage_h(a.h0_init + BH, shB, tid);
    __syncthreads();
    {
      int oct = tid >> 3, lane8 = tid & 7;
      int b = oct & 31, jj = oct >> 5;
      int j = bid*2 + jj;
      gru_oct(shA + b*LDP, shB + b*LDP, a.Wih1, a.Whh1, a.bih1, a.bhh1,
              j, lane8, h1g + b*Hsz + j);
    }
    gridbar(a.bar, bid);
    stage_h(h1g, shB, tid);
    __syncthreads();
    if (bid < CBLK){
      const int quad = tid >> 2, l4 = tid & 3;
      const int rg = quad & 31, bg = quad >> 5;
      const int rowbase = bid*128 + rg*4;
      const float* wr = a.Wout + (size_t)rowbase * Hsz;
      const float* hb = shB + bg*8*LDP;
      float acc[4][8];
      #pragma unroll
      for (int s = 0; s < 4; ++s)
        #pragma unroll
        for (int j = 0; j < 8; ++j) acc[s][j] = 0.f;
      #pragma unroll 2
      for (int i = 0; i < 32; ++i){
        const int k = i*16 + l4*4;
        float4 wv[4], hv[8];
        #pragma unroll
        for (int s = 0; s < 4; ++s) wv[s] = *(const float4*)(wr + (size_t)s*Hsz + k);
        #pragma unroll
        for (int j = 0; j < 8; ++j) hv[j] = *(const float4*)(hb + j*LDP + k);
        #pragma unroll
        for (int s = 0; s < 4; ++s)
          #pragma unroll
          for (int j = 0; j < 8; ++j) acc[s][j] = dot4acc(wv[s], hv[j], acc[s][j]);
      }
      #pragma unroll
      for (int s = 0; s < 4; ++s)
        #pragma unroll
        for (int j = 0; j < 8; ++j){
          float v = acc[s][j];
          v += __shfl_xor(v, 1); v += __shfl_xor(v, 2);
          acc[s][j] = v;
        }
      if (l4 == 0){
        float4 bv = *(const float4*)(a.bout + rowbase);
        float bb[4] = {bv.x, bv.y, bv.z, bv.w};
        #pragma unroll
        for (int j = 0; j < 8; ++j){
          float best = -3.4e38f; int bi = rowbase;
          #pragma unroll
          for (int s = 0; s < 4; ++s){
            float lv = acc[s][j] + bb[s];
            if (lv > best){ best = lv; bi = rowbase + s; }
          }
          unsigned u = __float_as_uint(best);
          unsigned key = (u & 0x80000000u) ? ~u : (u | 0x80000000u);
          lbest[rg*32 + bg*8 + j] =
              ((unsigned long long)key << 32) | (unsigned)(~(unsigned)bi);
        }
      }
      __syncthreads();
      if (tid < Bsz){
        unsigned long long m = lbest[tid];
        #pragma unroll 4
        for (int r = 1; r < 32; ++r){
          unsigned long long c = lbest[r*32 + tid];
          m = (c > m) ? c : m;
        }
        atomicMax(&a.packed[tid*16], m);
      }
    }
    gridbar(a.bar, bid);
  }
  if (bid == 0 && tid < Bsz){
    unsigned long long p = cload8(&a.packed[tid*16]);
    a.out[tid*T + (T-1)] = (float)((int)(~(unsigned)(p & 0xffffffffULL)));
  }
  int e = bid*NTHR + tid;
  if (e < BH/2){
    unsigned long long v0 = cload8((const unsigned long long*)h0g + e);
    unsigned long long v1 = cload8((const unsigned long long*)h1g + e);
    *((unsigned long long*)(a.out + Bsz*T) + e)      = v0;
    *((unsigned long long*)(a.out + Bsz*T + BH) + e) = v1;
  }
}

extern "C" void kernel_launch(void* const* d_in, const int* in_sizes, int n_in,
                              void* d_out, int out_size, void* d_ws, size_t ws_size,
                              hipStream_t stream){
  Args a;
  a.h0_init = (const float*)d_in[0];
  a.emb  = (const float*)d_in[1];
  a.Wih0 = (const float*)d_in[2];
  a.Whh0 = (const float*)d_in[3];
  a.bih0 = (const float*)d_in[4];
  a.bhh0 = (const float*)d_in[5];
  a.Wih1 = (const float*)d_in[6];
  a.Whh1 = (const float*)d_in[7];
  a.bih1 = (const float*)d_in[8];
  a.bhh1 = (const float*)d_in[9];
  a.Wout = (const float*)d_in[10];
  a.bout = (const float*)d_in[11];
  a.maxn = (const int*)d_in[12];
  a.out  = (float*)d_out;
  char* wsb = (char*)d_ws;
  a.hbuf   = (float*)(wsb + WS_HBUF);
  a.packed = (unsigned long long*)(wsb + WS_PACKED);
  a.plb    = (unsigned*)(wsb + WS_PLB);
  a.bar    = (unsigned*)(wsb + WS_BAR);
  a.cbar   = (unsigned*)(wsb + WS_CBAR);
  a.wpack  = (const unsigned*)(wsb + WS_WPACK);
  a.wnormE = (const float*)(wsb + WS_WNORM);

  // zero packed + plb + bar (12 KB); ws is re-poisoned 0xAA before every call
  hipMemsetAsync(wsb + WS_PACKED, 0, 12288, stream);

  void* params[] = { &a };
  if (ws_size >= (size_t)WS_NEEDED){
    hipMemsetAsync(wsb + WS_CBAR, 0, 4096, stream);   // cluster counters
    repack_kernel<<<CBLK, 512, 0, stream>>>(a.Wout, (unsigned*)a.wpack, (float*)a.wnormE);
    hipLaunchCooperativeKernel((void*)decoder_kernel, dim3(NBLK), dim3(NTHR),
                               params, 0, stream);
  } else {
    hipLaunchCooperativeKernel((void*)decoder_kernel_fb, dim3(NBLK), dim3(NTHR),
                               params, 0, stream);
  }
}

// Round 10
// 2597.965 us; speedup vs baseline: 1.0299x; 1.0299x over previous
//
#include <hip/hip_runtime.h>
#include <math.h>

#define NBLK 256
#define NTHR 512
#define Bsz  32
#define Hsz  512
#define Vsz  32000
#define BH   (Bsz*Hsz)
#define LDP  516         // fp32 row stride for fallback (512 + 4 pad)
#define LDPB 520         // bf16 row stride (1040B: 16B-aligned)
#define CBLK 250         // blocks doing logits (128 rows each)
#define EPS  0.0045f     // bf16 dot-product error coefficient (provable bound w/ margin)

// ---- ws layout (bytes) ----
#define WS_HBUF   0            // 2*BH floats = 131072
#define WS_PACKED 131072       // 32 x 128B (ull key64 per b)
#define WS_PLB    135168       // 32 x 128B (u32 lb-key per b, barrier-free monotone share)
#define WS_BAR    139264       // 17 x 128B tree barrier
#define WS_WPACK  143360       // 250*8*16*1024 = 32768000 (bf16 B-frags)
#define WS_WNORM  32911360     // 32000 floats (EPS * ||w_n||2)
#define WS_CBAR   33039360     // 32 x 128B monotone cluster counters
#define WS_NEEDED 33043456

// Seed for packed[b]: high word 0 (any real key32(lg)>=1 wins atomicMax),
// low word ~1u so an untouched slot decodes to tok=1 (valid), never -1.
#define PACKED_SEED 0x00000000FFFFFFFEull

typedef short short8 __attribute__((ext_vector_type(8)));
typedef float f32x4  __attribute__((ext_vector_type(4)));

struct Args {
  const float* h0_init;
  const float* emb;
  const float* Wih0; const float* Whh0; const float* bih0; const float* bhh0;
  const float* Wih1; const float* Whh1; const float* bih1; const float* bhh1;
  const float* Wout; const float* bout;
  const int*   maxn;
  float* out;
  float* hbuf;                 // [2*BH] h0,h1 (single-buffered)
  unsigned long long* packed;  // final fp32-key argmax per b (128B stride)
  unsigned* plb;               // per-b max lower-bound key (monotone, barrier-free)
  unsigned* bar;
  unsigned* cbar;              // 32 monotone cluster counters (128B stride)
  const unsigned* wpack;       // bf16 B-fragment packed Wout
  const float* wnormE;         // EPS * ||bf16(w_n)||_2
};

// ---- bf16 helpers (consistent RNE everywhere) ----
__device__ __forceinline__ unsigned short bf16_rne(float f){
  unsigned u = __float_as_uint(f);
  unsigned r = u + 0x7FFFu + ((u >> 16) & 1u);
  return (unsigned short)(r >> 16);
}
__device__ __forceinline__ float bf16v(float f){   // value after bf16 RNE rounding
  unsigned u = ((unsigned)bf16_rne(f)) << 16;
  return __uint_as_float(u);
}
__device__ __forceinline__ unsigned key32(float f){  // monotone float->uint
  unsigned u = __float_as_uint(f);
  return (u & 0x80000000u) ? ~u : (u | 0x80000000u);
}

// ---- coherent (L3-point) accessors ----
__device__ __forceinline__ unsigned long long cload8(const void* p){
  return __hip_atomic_load((const unsigned long long*)p,
                           __ATOMIC_RELAXED, __HIP_MEMORY_SCOPE_AGENT);
}
__device__ __forceinline__ unsigned cload4u(const unsigned* p){
  return __hip_atomic_load(p, __ATOMIC_RELAXED, __HIP_MEMORY_SCOPE_AGENT);
}
__device__ __forceinline__ void cstore4(float* p, float v){
  __hip_atomic_store(p, v, __ATOMIC_RELAXED, __HIP_MEMORY_SCOPE_AGENT);
}
__device__ __forceinline__ void cstore4u(unsigned* p, unsigned v){
  __hip_atomic_store(p, v, __ATOMIC_RELAXED, __HIP_MEMORY_SCOPE_AGENT);
}
__device__ __forceinline__ void cstore8(void* p, unsigned long long v){
  __hip_atomic_store((unsigned long long*)p, v,
                     __ATOMIC_RELAXED, __HIP_MEMORY_SCOPE_AGENT);
}

// non-temporal 16B load (one-time wpack hoist; avoid L2 pollution)
__device__ __forceinline__ short8 ntload8(const void* p){
  return __builtin_nontemporal_load((const short8*)p);
}

// ---- 2-level tree barrier (relaxed, contention-sharded), 256 blocks ----
__device__ __forceinline__ void gridbar(unsigned* bar, int bid){
  __syncthreads();
  if (threadIdx.x == 0){
    asm volatile("s_waitcnt vmcnt(0)" ::: "memory");
    const int g = bid & 7;
    unsigned* gcnt = bar + g*32;
    unsigned* root = bar + 8*32;
    unsigned* gen  = bar + (9+g)*32;
    unsigned mygen = __hip_atomic_load(gen, __ATOMIC_RELAXED, __HIP_MEMORY_SCOPE_AGENT);
    unsigned go = __hip_atomic_fetch_add(gcnt, 1u, __ATOMIC_RELAXED, __HIP_MEMORY_SCOPE_AGENT);
    if (go == 31u){
      unsigned ro = __hip_atomic_fetch_add(root, 1u, __ATOMIC_RELAXED, __HIP_MEMORY_SCOPE_AGENT);
      if (ro == 7u){
        #pragma unroll
        for (int i = 0; i < 8; ++i)
          __hip_atomic_store(bar + i*32, 0u, __ATOMIC_RELAXED, __HIP_MEMORY_SCOPE_AGENT);
        __hip_atomic_store(root, 0u, __ATOMIC_RELAXED, __HIP_MEMORY_SCOPE_AGENT);
        asm volatile("s_waitcnt vmcnt(0)" ::: "memory");
        #pragma unroll
        for (int i = 0; i < 8; ++i)
          __hip_atomic_fetch_add(bar + (9+i)*32, 1u, __ATOMIC_RELAXED, __HIP_MEMORY_SCOPE_AGENT);
      }
    }
    while (__hip_atomic_load(gen, __ATOMIC_RELAXED, __HIP_MEMORY_SCOPE_AGENT) == mygen){
      __builtin_amdgcn_s_sleep(1);
    }
  }
  __syncthreads();
}

// ---- monotone 8-block cluster barrier (no reset -> no reset/release race) ----
__device__ __forceinline__ void cluster_sync(unsigned* cnt, unsigned target){
  __syncthreads();
  if (threadIdx.x == 0){
    asm volatile("s_waitcnt vmcnt(0)" ::: "memory");
    __hip_atomic_fetch_add(cnt, 1u, __ATOMIC_RELAXED, __HIP_MEMORY_SCOPE_AGENT);
    while (__hip_atomic_load(cnt, __ATOMIC_RELAXED, __HIP_MEMORY_SCOPE_AGENT) < target){
      __builtin_amdgcn_s_sleep(1);
    }
  }
  __syncthreads();
}

// stage 32x512 floats global -> LDS as bf16 (row stride LDPB shorts).
// bf16_rne applied during staging: consumers see exactly the values the
// old fp32-stage + per-fragment-convert pipeline produced.
__device__ __forceinline__ void stage_h16(const float* g, unsigned short* s16, int tid){
  const unsigned long long* gd = (const unsigned long long*)g;
  #pragma unroll
  for (int n = 0; n < 16; ++n){
    int idx = n*512 + tid;          // float-pair index over 32*256
    int row = idx >> 8;
    int col2 = idx & 255;
    unsigned long long v = __hip_atomic_load(gd + idx, __ATOMIC_RELAXED,
                                             __HIP_MEMORY_SCOPE_AGENT);
    unsigned short b0 = bf16_rne(__uint_as_float((unsigned)v));
    unsigned short b1 = bf16_rne(__uint_as_float((unsigned)(v >> 32)));
    *(unsigned*)&s16[row*LDPB + col2*2] = (unsigned)b0 | ((unsigned)b1 << 16);
  }
}

// stage 32x512 floats global -> LDS fp32 (row stride LDP) — fallback kernel
__device__ __forceinline__ void stage_h(const float* g, float* s, int tid){
  const unsigned long long* gd = (const unsigned long long*)g;
  #pragma unroll
  for (int n = 0; n < 16; ++n){
    int idx = n*512 + tid;
    int row = idx >> 8;
    int col = idx & 255;
    unsigned long long v = __hip_atomic_load(gd + idx, __ATOMIC_RELAXED,
                                             __HIP_MEMORY_SCOPE_AGENT);
    *(unsigned long long*)(s + row*LDP + col*2) = v;
  }
}

// stage one 512-float row global -> LDS, coherent 8B loads
__device__ __forceinline__ void stage_row(const float* g, float* s, int tid){
  if (tid < 256){
    unsigned long long v = __hip_atomic_load((const unsigned long long*)g + tid,
                                             __ATOMIC_RELAXED, __HIP_MEMORY_SCOPE_AGENT);
    *(unsigned long long*)(s + tid*2) = v;
  }
}

__device__ __forceinline__ float red8(float v){
  v += __shfl_xor(v, 1); v += __shfl_xor(v, 2); v += __shfl_xor(v, 4);
  return v;
}
__device__ __forceinline__ float dot4acc(float4 w, float4 x, float acc){
  return fmaf(w.x,x.x, fmaf(w.y,x.y, fmaf(w.z,x.z, fmaf(w.w,x.w, acc))));
}

// 3-gate dot-512 over one row (8 lanes per oct). Same summation order
// everywhere -> h trajectories bitwise identical across restructurings.
__device__ __forceinline__ void dot3(const float* row, const float* W, int j,
                                     int lane8, float& g0, float& g1, float& g2){
  const float* w = W + (size_t)j * Hsz;
  float a0 = 0.f, a1 = 0.f, a2 = 0.f;
  #pragma unroll 4
  for (int i = 0; i < 16; ++i){
    int k = i*32 + lane8*4;
    float4 v = *(const float4*)(row + k);
    a0 = dot4acc(*(const float4*)(w + k),            v, a0);
    a1 = dot4acc(*(const float4*)(w + 512*512 + k),  v, a1);
    a2 = dot4acc(*(const float4*)(w + 2*512*512 + k),v, a2);
  }
  g0 = red8(a0); g1 = red8(a1); g2 = red8(a2);
}

__device__ __forceinline__ void gru_oct(
    const float* xrow, const float* hrow,
    const float* Wih, const float* Whh,
    const float* bih, const float* bhh,
    int j, int lane8, float* hout_g)
{
  const float* wir = Wih + (size_t)j * Hsz;
  const float* whr = Whh + (size_t)j * Hsz;
  float ar=0.f, az=0.f, an=0.f, hr=0.f, hz=0.f, hn=0.f;
  #pragma unroll 4
  for (int i = 0; i < 16; ++i){
    int k = i*32 + lane8*4;
    float4 xv = *(const float4*)(xrow + k);
    float4 hv = *(const float4*)(hrow + k);
    ar = dot4acc(*(const float4*)(wir + k),            xv, ar);
    az = dot4acc(*(const float4*)(wir + 512*512 + k),  xv, az);
    an = dot4acc(*(const float4*)(wir + 2*512*512 + k),xv, an);
    hr = dot4acc(*(const float4*)(whr + k),            hv, hr);
    hz = dot4acc(*(const float4*)(whr + 512*512 + k),  hv, hz);
    hn = dot4acc(*(const float4*)(whr + 2*512*512 + k),hv, hn);
  }
  ar = red8(ar); az = red8(az); an = red8(an);
  hr = red8(hr); hz = red8(hz); hn = red8(hn);
  if (lane8 == 0){
    float r = 1.f/(1.f + expf(-(ar + bih[j]       + hr + bhh[j])));
    float z = 1.f/(1.f + expf(-(az + bih[Hsz+j]   + hz + bhh[Hsz+j])));
    float n = tanhf(an + bih[2*Hsz+j] + r*(hn + bhh[2*Hsz+j]));
    cstore4(hout_g, (1.f - z)*n + z*hrow[j]);
  }
}

// ================= repack: Wout fp32 -> bf16 B-fragments + row norms =================
__global__ __launch_bounds__(512) void repack_kernel(const float* __restrict__ Wout,
                                                     unsigned* __restrict__ wpack,
                                                     float* __restrict__ wnormE){
  const int rb = blockIdx.x;            // 0..249
  const int g = threadIdx.x >> 6;       // wave
  const int lane = threadIdx.x & 63;
  const int n = rb*128 + g*16 + (lane & 15);
  const int kq = (lane >> 4) * 8;
  float sumsq = 0.f;
  for (int c = 0; c < 16; ++c){
    const float* p = Wout + (size_t)n*512 + c*32 + kq;
    float4 f0 = *(const float4*)p;
    float4 f1 = *(const float4*)(p + 4);
    unsigned short s0 = bf16_rne(f0.x), s1 = bf16_rne(f0.y),
                   s2 = bf16_rne(f0.z), s3 = bf16_rne(f0.w),
                   s4 = bf16_rne(f1.x), s5 = bf16_rne(f1.y),
                   s6 = bf16_rne(f1.z), s7 = bf16_rne(f1.w);
    float v;
    v = __uint_as_float(((unsigned)s0)<<16); sumsq += v*v;
    v = __uint_as_float(((unsigned)s1)<<16); sumsq += v*v;
    v = __uint_as_float(((unsigned)s2)<<16); sumsq += v*v;
    v = __uint_as_float(((unsigned)s3)<<16); sumsq += v*v;
    v = __uint_as_float(((unsigned)s4)<<16); sumsq += v*v;
    v = __uint_as_float(((unsigned)s5)<<16); sumsq += v*v;
    v = __uint_as_float(((unsigned)s6)<<16); sumsq += v*v;
    v = __uint_as_float(((unsigned)s7)<<16); sumsq += v*v;
    uint4 u;
    u.x = (unsigned)s0 | ((unsigned)s1<<16);
    u.y = (unsigned)s2 | ((unsigned)s3<<16);
    u.z = (unsigned)s4 | ((unsigned)s5<<16);
    u.w = (unsigned)s6 | ((unsigned)s7<<16);
    *(uint4*)(wpack + (size_t)(((rb*8+g)*16 + c))*256 + lane*4) = u;
  }
  sumsq += __shfl_xor(sumsq, 16);
  sumsq += __shfl_xor(sumsq, 32);
  if (lane < 16) wnormE[n] = EPS * sqrtf(sumsq);
}

// ================= main cooperative kernel (MFMA path) =================
// Batch-cluster decomposition (R8): block bid owns batch b = bid>>3, j-range
// [s*64,+64), s = bid&7. Barriers/step: 1 cluster sync + 2 global bars.
// R9: bf16-resident shB16, direct ds_read A-fragments.
// R10: register-resident candidate pruning — the 8KB ubq buffer, its writes,
// and the 4096-entry scan are deleted. After the lbmaxL sync each thread
// checks its own 8 (m,n) results with EXACT fp32 ub (tighter than the old
// bf16-ru quantized ub, still sound: ub >= lg >= lb(argmax)), pushing
// survivors + ub-key to candList/candUB. Rescore set shrinks; results
// unchanged (exact rescore of a sound superset). h and tokens bitwise
// identical to R8/R9. AGPR-pinned wpack fragments (R6). PACKED_SEED.
__global__ __launch_bounds__(NTHR, 1) void decoder_kernel(Args a){
  const int tid = threadIdx.x;
  const int bid = blockIdx.x;
  const int wave = tid >> 6;
  const int lane = tid & 63;
  const int b  = bid >> 3;          // owned batch
  const int s  = bid & 7;           // cluster sub-index
  const int j0 = s * 64;            // owned j-range start
  const int T = a.maxn[0];
  float* h0g = a.hbuf;
  float* h1g = a.hbuf + BH;

  __shared__ __align__(16) unsigned short shB16[Bsz*LDPB];  // h1 bf16 mirror (33 KB)
  __shared__ float h0row[LDP];                   // h0_t[b] fp32 (cluster-staged)
  __shared__ float h1row[LDP];                   // h1_t[b] fp32 (for gh1 dot)
  __shared__ float ghA[3][64];                   // gh0 gates for owned j's
  __shared__ float ghB[3][64];                   // gh1 gates for owned j's
  __shared__ float h0own[64];                    // h0_{t}[b][owned j]
  __shared__ float h1own[64];                    // h1_{t}[b][owned j]
  __shared__ unsigned lbmaxL[32];
  __shared__ unsigned maxlbL[32];
  __shared__ float hnormL[32];
  __shared__ int sh_tok0;
  __shared__ int candCnt;
  __shared__ int candList[512];
  __shared__ unsigned candUB[512];

  // ---- hoisted step-invariant state: wave's 16 B-fragments -> AGPRs ----
  short8 bw[16];
  float bias = 0.f, wn = 0.f;
  if (bid < CBLK){
    const unsigned* wbase = a.wpack + (size_t)((bid*8 + wave)*16)*256 + lane*4;
    #pragma unroll
    for (int c = 0; c < 16; ++c){
      bw[c] = ntload8(wbase + c*256);
      asm volatile("" : "+a"(bw[c]));            // pin to AGPR class
    }
    int n = bid*128 + wave*16 + (lane & 15);
    bias = a.bout[n];
    wn = a.wnormE[n];
  }

  // ---- prologue: own-h init, h0row/h1row stage, gh for step 0 ----
  if (tid < 64){
    h0own[tid] = a.h0_init[(size_t)b*Hsz + j0 + tid];
    h1own[tid] = a.h0_init[BH + (size_t)b*Hsz + j0 + tid];
  }
  stage_row(a.h0_init + (size_t)b*Hsz, h0row, tid);
  stage_row(a.h0_init + BH + (size_t)b*Hsz, h1row, tid);
  __syncthreads();
  {
    int oct = tid >> 3, lane8 = tid & 7;
    int j = j0 + oct;
    float hr, hz, hn;  dot3(h0row, a.Whh0, j, lane8, hr, hz, hn);
    float kr, kz, kn;  dot3(h1row, a.Whh1, j, lane8, kr, kz, kn);
    if (lane8 == 0){
      ghA[0][oct] = hr; ghA[1][oct] = hz; ghA[2][oct] = hn;
      ghB[0][oct] = kr; ghB[1][oct] = kz; ghB[2][oct] = kn;
    }
  }
  __syncthreads();

  unsigned ctarget = 0;
  for (int t = 0; t < T; ++t){
    // ---- Phase A: GRU0 input-side for owned batch (no stage) ----
    if (tid == 0){
      int tok = 1;
      if (t > 0){
        tok = (int)(~(unsigned)(cload8(&a.packed[b*16]) & 0xffffffffULL));
        if ((unsigned)tok >= (unsigned)Vsz) tok = 1;  // safety clamp
      }
      sh_tok0 = tok;
    }
    __syncthreads();
    {
      int oct = tid >> 3, lane8 = tid & 7;
      int j = j0 + oct;
      const float* xrow = a.emb + (size_t)sh_tok0 * Hsz;
      float ar, az, an;  dot3(xrow, a.Wih0, j, lane8, ar, az, an);
      if (lane8 == 0){
        float hr = ghA[0][oct], hz = ghA[1][oct], hn = ghA[2][oct];
        float r = 1.f/(1.f + expf(-(ar + a.bih0[j]       + hr + a.bhh0[j])));
        float z = 1.f/(1.f + expf(-(az + a.bih0[Hsz+j]   + hz + a.bhh0[Hsz+j])));
        float n = tanhf(an + a.bih0[2*Hsz+j] + r*(hn + a.bhh0[2*Hsz+j]));
        float hnew = (1.f - z)*n + z*h0own[oct];
        cstore4(h0g + (size_t)b*Hsz + j, hnew);
        h0own[oct] = hnew;
      }
    }
    ctarget += 8;
    cluster_sync(a.cbar + b*32, ctarget);      // 8-block h0 exchange

    // ---- Phase B: harvest token t-1 (cluster leader), seed packed/plb;
    //      2KB cluster stage of h0_t[b]; GRU1 input-side + combine ----
    if (s == 0 && tid == 0){
      if (t > 0){
        unsigned long long p = cload8(&a.packed[b*16]);
        int tok = (int)(~(unsigned)(p & 0xffffffffULL));
        a.out[(size_t)b*T + (t-1)] = (float)tok;
      }
      cstore8(&a.packed[b*16], PACKED_SEED);
      cstore4u(&a.plb[b*32], 0u);
    }
    stage_row(h0g + (size_t)b*Hsz, h0row, tid);  // h0_t[b]
    __syncthreads();
    {
      int oct = tid >> 3, lane8 = tid & 7;
      int j = j0 + oct;
      float ar, az, an;  dot3(h0row, a.Wih1, j, lane8, ar, az, an);
      if (lane8 == 0){
        float hr = ghB[0][oct], hz = ghB[1][oct], hn = ghB[2][oct];
        float r = 1.f/(1.f + expf(-(ar + a.bih1[j]       + hr + a.bhh1[j])));
        float z = 1.f/(1.f + expf(-(az + a.bih1[Hsz+j]   + hz + a.bhh1[Hsz+j])));
        float n = tanhf(an + a.bih1[2*Hsz+j] + r*(hn + a.bhh1[2*Hsz+j]));
        float hnew = (1.f - z)*n + z*h1own[oct];
        cstore4(h1g + (size_t)b*Hsz + j, hnew);
        h1own[oct] = hnew;
      }
    }
    gridbar(a.bar, bid);

    // ---- Phase C: stage h1->shB16 (bf16, CBLK only) + h1row (all);
    //      gh precompute for t+1; MFMA logits + bounds + prune + rescore ----
    if (bid < CBLK) stage_h16(h1g, shB16, tid);
    stage_row(h1g + (size_t)b*Hsz, h1row, tid);  // h1_t[b] fp32
    if (tid < 32) lbmaxL[tid] = 0u;
    if (tid == 0) candCnt = 0;
    __syncthreads();
    // gh precompute (all blocks): h0row = h0_t[b] (staged in B, untouched),
    // h1row = h1_t[b]. Same dot3 order as R8/R9 -> bitwise identical.
    {
      int oct = tid >> 3, lane8 = tid & 7;
      int j = j0 + oct;
      float hr, hz, hn;  dot3(h0row, a.Whh0, j, lane8, hr, hz, hn);
      float kr, kz, kn;  dot3(h1row, a.Whh1, j, lane8, kr, kz, kn);
      if (lane8 == 0){
        ghA[0][oct] = hr; ghA[1][oct] = hz; ghA[2][oct] = hn;
        ghB[0][oct] = kr; ghB[1][oct] = kz; ghB[2][oct] = kn;
      }
    }
    if (bid < CBLK){
      // re-assert AGPR residency for the loop-carried fragment values
      #pragma unroll
      for (int c = 0; c < 16; ++c) asm volatile("" : "+a"(bw[c]));

      // h-norms from bf16-resident shB16 (values ARE bf16v(h1))
      if (tid < 256){
        int hb = tid >> 3, lane8 = tid & 7;
        float sq = 0.f;
        #pragma unroll
        for (int i = 0; i < 8; ++i){
          short8 sv = *(const short8*)&shB16[hb*LDPB + i*64 + lane8*8];
          #pragma unroll
          for (int q = 0; q < 8; ++q){
            float v = __uint_as_float(((unsigned)(unsigned short)sv[q]) << 16);
            sq = fmaf(v, v, sq);
          }
        }
        sq = red8(sq);
        if (lane8 == 0) hnormL[hb] = sqrtf(sq);
      }

      // MFMA: A-operand via direct ds_read_b128 of shB16 (no af staging)
      f32x4 accs[2];
      #pragma unroll
      for (int mt = 0; mt < 2; ++mt){
        f32x4 acc = {0.f, 0.f, 0.f, 0.f};
        const unsigned short* arow = shB16 + (mt*16 + (lane & 15))*LDPB + (lane >> 4)*8;
        #pragma unroll
        for (int c = 0; c < 16; ++c){
          short8 av = *(const short8*)(arow + c*32);
          acc = __builtin_amdgcn_mfma_f32_16x16x32_bf16(av, bw[c], acc, 0, 0, 0);
        }
        accs[mt] = acc;
      }
      __syncthreads();   // hnormL ready for epilogue
      // epilogue: lb max-reduce only (no ub quantize/store — R10)
      // D[m][n], m = mt*16 + (lane>>4)*4 + r, n = bid*128 + wave*16 + (lane&15)
      {
        int quad = lane >> 4;
        #pragma unroll
        for (int mt = 0; mt < 2; ++mt){
          #pragma unroll
          for (int r = 0; r < 4; ++r){
            int m = mt*16 + quad*4 + r;
            float lg = accs[mt][r] + bias;
            float lb = lg - wn * hnormL[m];
            unsigned lk = key32(lb), o;
            o = __shfl_xor(lk, 1); lk = lk > o ? lk : o;
            o = __shfl_xor(lk, 2); lk = lk > o ? lk : o;
            o = __shfl_xor(lk, 4); lk = lk > o ? lk : o;
            o = __shfl_xor(lk, 8); lk = lk > o ? lk : o;
            if ((lane & 15) == 0) atomicMax(&lbmaxL[m], lk);
          }
        }
      }
      __syncthreads();
      // publish local max-lb to global plb (fire-and-forget; monotone tighten)
      if (tid < 32) atomicMax(&a.plb[tid*32], lbmaxL[tid]);
      // register-resident candidate check: exact fp32 ub vs local lbmax
      {
        int n_loc = wave*16 + (lane & 15);
        int quad = lane >> 4;
        #pragma unroll
        for (int mt = 0; mt < 2; ++mt){
          #pragma unroll
          for (int r = 0; r < 4; ++r){
            int m = mt*16 + quad*4 + r;
            float lg = accs[mt][r] + bias;
            float ub = lg + wn * hnormL[m];
            unsigned uk = key32(ub);
            if (uk >= lbmaxL[m]){
              int pos = atomicAdd(&candCnt, 1);
              if (pos < 512){ candList[pos] = n_loc*32 + m; candUB[pos] = uk; }
            }
          }
        }
      }
      __syncthreads();
      // re-read plb (other blocks' publishes have been landing meanwhile)
      if (tid < 32){
        unsigned g = cload4u(&a.plb[tid*32]);
        unsigned l = lbmaxL[tid];
        maxlbL[tid] = g > l ? g : l;
      }
      __syncthreads();
      // exact fp32 rescore of surviving candidates (wave-per-candidate).
      // h-row read from global h1g via agent-scope loads (L2-resident, few).
      auto rescore = [&](int cidx, unsigned uk){
        int n_loc = cidx >> 5, rb = cidx & 31;
        if (uk < maxlbL[rb]) return;             // plb-tightened skip
        int n = bid*128 + n_loc;
        const float* wrow = a.Wout + (size_t)n*512 + lane*8;
        const unsigned long long* hq =
            (const unsigned long long*)(h1g + (size_t)rb*Hsz) + lane*4;
        unsigned long long q0 = cload8(hq),     q1 = cload8(hq + 1);
        unsigned long long q2 = cload8(hq + 2), q3 = cload8(hq + 3);
        float4 x0 = make_float4(__uint_as_float((unsigned)q0),
                                __uint_as_float((unsigned)(q0 >> 32)),
                                __uint_as_float((unsigned)q1),
                                __uint_as_float((unsigned)(q1 >> 32)));
        float4 x1 = make_float4(__uint_as_float((unsigned)q2),
                                __uint_as_float((unsigned)(q2 >> 32)),
                                __uint_as_float((unsigned)q3),
                                __uint_as_float((unsigned)(q3 >> 32)));
        float4 w0 = *(const float4*)wrow,      w1 = *(const float4*)(wrow + 4);
        float d = dot4acc(w0, x0, 0.f);
        d = dot4acc(w1, x1, d);
        d += __shfl_xor(d, 1);  d += __shfl_xor(d, 2);  d += __shfl_xor(d, 4);
        d += __shfl_xor(d, 8);  d += __shfl_xor(d, 16); d += __shfl_xor(d, 32);
        if (lane == 0){
          float lg = d + a.bout[n];
          unsigned long long key =
              (((unsigned long long)key32(lg)) << 32) | (unsigned)(~(unsigned)n);
          atomicMax(&a.packed[rb*16], key);
        }
      };
      int nc = candCnt;
      if (nc <= 512){
        for (int ci = wave; ci < nc; ci += 8) rescore(candList[ci], candUB[ci]);
      } else {
        // overflow safety net (cannot trigger with these margins): exact-check all
        for (int ci = wave; ci < 4096; ci += 8) rescore(ci, 0xFFFFFFFFu);
      }
    }
    gridbar(a.bar, bid);
  }

  // ---- final harvest + final hidden states ----
  if (bid == 0 && tid < Bsz){
    unsigned long long p = cload8(&a.packed[tid*16]);
    int tok = (int)(~(unsigned)(p & 0xffffffffULL));
    a.out[tid*T + (T-1)] = (float)tok;
  }
  int e = bid*NTHR + tid;
  if (e < BH/2){
    unsigned long long v0 = cload8((const unsigned long long*)h0g + e);
    unsigned long long v1 = cload8((const unsigned long long*)h1g + e);
    *((unsigned long long*)(a.out + Bsz*T) + e)      = v0;
    *((unsigned long long*)(a.out + Bsz*T + BH) + e) = v1;
  }
}

// ================= fallback (round-4 fp32 path) if ws too small =================
__global__ __launch_bounds__(NTHR, 1) void decoder_kernel_fb(Args a){
  const int tid = threadIdx.x;
  const int bid = blockIdx.x;
  const int T = a.maxn[0];
  float* h0g = a.hbuf;
  float* h1g = a.hbuf + BH;
  __shared__ float shA[Bsz*LDP];
  __shared__ float shB[Bsz*LDP];
  __shared__ unsigned long long lbest[32*32];
  __shared__ int sh_tok[Bsz];

  for (int t = 0; t < T; ++t){
    if (t == 0) stage_h(a.h0_init, shA, tid);
    if (tid < Bsz){
      int tok;
      if (t == 0) tok = 1;
      else {
        tok = (int)(~(unsigned)(cload8(&a.packed[tid*16]) & 0xffffffffULL));
        if ((unsigned)tok >= (unsigned)Vsz) tok = 1;
      }
      sh_tok[tid] = tok;
    }
    __syncthreads();
    {
      int oct = tid >> 3, lane8 = tid & 7;
      int b = oct & 31, jj = oct >> 5;
      int j = bid*2 + jj;
      const float* xrow = a.emb + (size_t)sh_tok[b] * Hsz;
      gru_oct(xrow, shA + b*LDP, a.Wih0, a.Whh0, a.bih0, a.bhh0,
              j, lane8, h0g + b*Hsz + j);
    }
    gridbar(a.bar, bid);
    if (bid == 0 && tid < Bsz){
      if (t > 0){
        unsigned long long p = cload8(&a.packed[tid*16]);
        a.out[tid*T + (t-1)] = (float)((int)(~(unsigned)(p & 0xffffffffULL)));
      }
      cstore8(&a.packed[tid*16], PACKED_SEED);
    }
    stage_h(h0g, shA, tid);
    if (t == 0) stage_h(a.h0_init + BH, shB, tid);
    __syncthreads();
    {
      int oct = tid >> 3, lane8 = tid & 7;
      int b = oct & 31, jj = oct >> 5;
      int j = bid*2 + jj;
      gru_oct(shA + b*LDP, shB + b*LDP, a.Wih1, a.Whh1, a.bih1, a.bhh1,
              j, lane8, h1g + b*Hsz + j);
    }
    gridbar(a.bar, bid);
    stage_h(h1g, shB, tid);
    __syncthreads();
    if (bid < CBLK){
      const int quad = tid >> 2, l4 = tid & 3;
      const int rg = quad & 31, bg = quad >> 5;
      const int rowbase = bid*128 + rg*4;
      const float* wr = a.Wout + (size_t)rowbase * Hsz;
      const float* hb = shB + bg*8*LDP;
      float acc[4][8];
      #pragma unroll
      for (int s = 0; s < 4; ++s)
        #pragma unroll
        for (int j = 0; j < 8; ++j) acc[s][j] = 0.f;
      #pragma unroll 2
      for (int i = 0; i < 32; ++i){
        const int k = i*16 + l4*4;
        float4 wv[4], hv[8];
        #pragma unroll
        for (int s = 0; s < 4; ++s) wv[s] = *(const float4*)(wr + (size_t)s*Hsz + k);
        #pragma unroll
        for (int j = 0; j < 8; ++j) hv[j] = *(const float4*)(hb + j*LDP + k);
        #pragma unroll
        for (int s = 0; s < 4; ++s)
          #pragma unroll
          for (int j = 0; j < 8; ++j) acc[s][j] = dot4acc(wv[s], hv[j], acc[s][j]);
      }
      #pragma unroll
      for (int s = 0; s < 4; ++s)
        #pragma unroll
        for (int j = 0; j < 8; ++j){
          float v = acc[s][j];
          v += __shfl_xor(v, 1); v += __shfl_xor(v, 2);
          acc[s][j] = v;
        }
      if (l4 == 0){
        float4 bv = *(const float4*)(a.bout + rowbase);
        float bb[4] = {bv.x, bv.y, bv.z, bv.w};
        #pragma unroll
        for (int j = 0; j < 8; ++j){
          float best = -3.4e38f; int bi = rowbase;
          #pragma unroll
          for (int s = 0; s < 4; ++s){
            float lv = acc[s][j] + bb[s];
            if (lv > best){ best = lv; bi = rowbase + s; }
          }
          unsigned u = __float_as_uint(best);
          unsigned key = (u & 0x80000000u) ? ~u : (u | 0x80000000u);
          lbest[rg*32 + bg*8 + j] =
              ((unsigned long long)key << 32) | (unsigned)(~(unsigned)bi);
        }
      }
      __syncthreads();
      if (tid < Bsz){
        unsigned long long m = lbest[tid];
        #pragma unroll 4
        for (int r = 1; r < 32; ++r){
          unsigned long long c = lbest[r*32 + tid];
          m = (c > m) ? c : m;
        }
        atomicMax(&a.packed[tid*16], m);
      }
    }
    gridbar(a.bar, bid);
  }
  if (bid == 0 && tid < Bsz){
    unsigned long long p = cload8(&a.packed[tid*16]);
    a.out[tid*T + (T-1)] = (float)((int)(~(unsigned)(p & 0xffffffffULL)));
  }
  int e = bid*NTHR + tid;
  if (e < BH/2){
    unsigned long long v0 = cload8((const unsigned long long*)h0g + e);
    unsigned long long v1 = cload8((const unsigned long long*)h1g + e);
    *((unsigned long long*)(a.out + Bsz*T) + e)      = v0;
    *((unsigned long long*)(a.out + Bsz*T + BH) + e) = v1;
  }
}

extern "C" void kernel_launch(void* const* d_in, const int* in_sizes, int n_in,
                              void* d_out, int out_size, void* d_ws, size_t ws_size,
                              hipStream_t stream){
  Args a;
  a.h0_init = (const float*)d_in[0];
  a.emb  = (const float*)d_in[1];
  a.Wih0 = (const float*)d_in[2];
  a.Whh0 = (const float*)d_in[3];
  a.bih0 = (const float*)d_in[4];
  a.bhh0 = (const float*)d_in[5];
  a.Wih1 = (const float*)d_in[6];
  a.Whh1 = (const float*)d_in[7];
  a.bih1 = (const float*)d_in[8];
  a.bhh1 = (const float*)d_in[9];
  a.Wout = (const float*)d_in[10];
  a.bout = (const float*)d_in[11];
  a.maxn = (const int*)d_in[12];
  a.out  = (float*)d_out;
  char* wsb = (char*)d_ws;
  a.hbuf   = (float*)(wsb + WS_HBUF);
  a.packed = (unsigned long long*)(wsb + WS_PACKED);
  a.plb    = (unsigned*)(wsb + WS_PLB);
  a.bar    = (unsigned*)(wsb + WS_BAR);
  a.cbar   = (unsigned*)(wsb + WS_CBAR);
  a.wpack  = (const unsigned*)(wsb + WS_WPACK);
  a.wnormE = (const float*)(wsb + WS_WNORM);

  // zero packed + plb + bar (12 KB); ws is re-poisoned 0xAA before every call
  hipMemsetAsync(wsb + WS_PACKED, 0, 12288, stream);

  void* params[] = { &a };
  if (ws_size >= (size_t)WS_NEEDED){
    hipMemsetAsync(wsb + WS_CBAR, 0, 4096, stream);   // cluster counters
    repack_kernel<<<CBLK, 512, 0, stream>>>(a.Wout, (unsigned*)a.wpack, (float*)a.wnormE);
    hipLaunchCooperativeKernel((void*)decoder_kernel, dim3(NBLK), dim3(NTHR),
                               params, 0, stream);
  } else {
    hipLaunchCooperativeKernel((void*)decoder_kernel_fb, dim3(NBLK), dim3(NTHR),
                               params, 0, stream);
  }
}